// Round 1
// baseline (716.180 us; speedup 1.0000x reference)
//
#include <hip/hip_runtime.h>

typedef unsigned short u16;
typedef unsigned int u32;
typedef float f32x4 __attribute__((ext_vector_type(4)));
typedef __bf16 bf16x8 __attribute__((ext_vector_type(8)));

// ---------- helpers ----------
__device__ __forceinline__ u16 f2bf(float f) {
  u32 u = __float_as_uint(f);
  u += 0x7fffu + ((u >> 16) & 1u);
  return (u16)(u >> 16);
}

__device__ __forceinline__ void gload16(const u16* g, u16* l) {
  // async global->LDS, 16B per lane; LDS dest = wave-uniform base + lane*16
  __builtin_amdgcn_global_load_lds(
      (__attribute__((address_space(1))) void*)(u16*)g,
      (__attribute__((address_space(3))) void*)l, 16, 0, 0);
}

// ---------- fp32 -> bf16 conversion (weights) ----------
__global__ __launch_bounds__(256) void cvt_bf16(const float* __restrict__ in,
                                                u16* __restrict__ o, int n4) {
  int i = blockIdx.x * 256 + threadIdx.x;
  if (i >= n4) return;
  float4 f = reinterpret_cast<const float4*>(in)[i];
  u32 lo = (u32)f2bf(f.x) | ((u32)f2bf(f.y) << 16);
  u32 hi = (u32)f2bf(f.z) | ((u32)f2bf(f.w) << 16);
  reinterpret_cast<uint2*>(o)[i] = make_uint2(lo, hi);
}

// ---------- LayerNorm (row of 768) -> bf16 ----------
__global__ __launch_bounds__(256) void ln_bf16(const float* __restrict__ x,
                                               const float* __restrict__ g,
                                               const float* __restrict__ b,
                                               u16* __restrict__ o) {
  const int row = blockIdx.x;
  const int t = threadIdx.x;
  const float* xr = x + (size_t)row * 768;
  float a0 = xr[t], a1 = xr[t + 256], a2 = xr[t + 512];
  float s = a0 + a1 + a2;
  float ss = a0 * a0 + a1 * a1 + a2 * a2;
#pragma unroll
  for (int m = 1; m < 64; m <<= 1) {
    s += __shfl_xor(s, m);
    ss += __shfl_xor(ss, m);
  }
  __shared__ float sb[8];
  if ((t & 63) == 0) { sb[t >> 6] = s; sb[4 + (t >> 6)] = ss; }
  __syncthreads();
  s = sb[0] + sb[1] + sb[2] + sb[3];
  ss = sb[4] + sb[5] + sb[6] + sb[7];
  const float mu = s * (1.0f / 768.0f);
  const float var = ss * (1.0f / 768.0f) - mu * mu;
  const float rs = rsqrtf(var + 1e-5f);
  u16* orow = o + (size_t)row * 768;
  orow[t]       = f2bf((a0 - mu) * rs * g[t] + b[t]);
  orow[t + 256] = f2bf((a1 - mu) * rs * g[t + 256] + b[t + 256]);
  orow[t + 512] = f2bf((a2 - mu) * rs * g[t + 512] + b[t + 512]);
}

// ---------- GEMM: C[M,N] = A[M,K](bf16) @ W[N,K]^T(bf16), fused epilogues ----------
enum { EPI_QKV = 0, EPI_PROJ = 1, EPI_GELU = 2, EPI_OUT = 3 };

template <int EPI>
__global__ __launch_bounds__(256) void gemm_bt(
    const u16* __restrict__ A, const u16* __restrict__ W,
    const float* __restrict__ bias, const float* __restrict__ res,
    float* __restrict__ outf, u16* __restrict__ outb,
    u16* __restrict__ outq, u16* __restrict__ outk, u16* __restrict__ outv,
    int M, int N, int K) {
  __shared__ u16 As[128 * 32];
  __shared__ u16 Bs[128 * 32];
  const int tid = threadIdx.x;
  const int w = tid >> 6, l = tid & 63;
  const int wr = w >> 1, wc = w & 1;
  const int bm = blockIdx.x, bn = blockIdx.y;
  const int lg = l >> 4, lc = l & 15;

  f32x4 acc[4][4] = {};

  const int srow = l >> 2;       // 0..15 within a 16-row chunk
  const int scol = (l & 3) * 8;  // 0,8,16,24
  const u16* Ab = A + (size_t)(bm * 128) * K;
  const u16* Wb = W + (size_t)(bn * 128) * K;

  for (int kt = 0; kt < K; kt += 32) {
    __syncthreads();
#pragma unroll
    for (int i = 0; i < 2; ++i) {
      const int c = w * 2 + i;  // chunk 0..7, covers rows c*16..c*16+15
      gload16(Ab + (size_t)(c * 16 + srow) * K + kt + scol, &As[c * 512]);
      gload16(Wb + (size_t)(c * 16 + srow) * K + kt + scol, &Bs[c * 512]);
    }
    __syncthreads();
    bf16x8 af[4], bfv[4];
#pragma unroll
    for (int mi = 0; mi < 4; ++mi)
      af[mi] = *reinterpret_cast<const bf16x8*>(&As[(wr * 64 + mi * 16 + lc) * 32 + lg * 8]);
#pragma unroll
    for (int ni = 0; ni < 4; ++ni)
      bfv[ni] = *reinterpret_cast<const bf16x8*>(&Bs[(wc * 64 + ni * 16 + lc) * 32 + lg * 8]);
#pragma unroll
    for (int mi = 0; mi < 4; ++mi)
#pragma unroll
      for (int ni = 0; ni < 4; ++ni)
        acc[mi][ni] = __builtin_amdgcn_mfma_f32_16x16x32_bf16(af[mi], bfv[ni], acc[mi][ni], 0, 0, 0);
  }

  const int rbase = bm * 128 + wr * 64;
  const int cbase = bn * 128 + wc * 64;
#pragma unroll
  for (int mi = 0; mi < 4; ++mi) {
#pragma unroll
    for (int ni = 0; ni < 4; ++ni) {
#pragma unroll
      for (int r = 0; r < 4; ++r) {
        const int i = rbase + mi * 16 + lg * 4 + r;
        const int j = cbase + ni * 16 + lc;
        float v = acc[mi][ni][r] + bias[j];
        if constexpr (EPI == EPI_QKV) {
          const int t = j / 768;
          const int rr = j - t * 768;
          const int h = rr >> 6, hd = rr & 63;
          const int bb = i >> 9, ssi = i & 511;
          u16* dst = (t == 0) ? outq : (t == 1) ? outk : outv;
          if (t == 0) v *= 0.125f;  // HD^-0.5
          dst[((size_t)(bb * 12 + h) * 512 + ssi) * 64 + hd] = f2bf(v);
        } else if constexpr (EPI == EPI_PROJ) {
          outf[(size_t)i * 768 + j] = v + res[(size_t)i * 768 + j];
        } else if constexpr (EPI == EPI_GELU) {
          float gl = 0.5f * v * (1.0f + erff(v * 0.70710678118654752f));
          outb[(size_t)i * 3072 + j] = f2bf(gl);
        } else {  // EPI_OUT
          outf[(size_t)i * 768 + j] = v + res[(size_t)i * 768 + j];
        }
      }
    }
  }
}

// ---------- attention: per block = one (b,h), 64 q-rows ----------
#define PSTR 520  // 512 + 8 pad: keeps 16B alignment, spreads banks

__global__ __launch_bounds__(256) void attn_fwd(const u16* __restrict__ q,
                                                const u16* __restrict__ k,
                                                const u16* __restrict__ v,
                                                const float* __restrict__ eb,
                                                u16* __restrict__ o) {
  __shared__ u16 P[64 * PSTR];
  __shared__ u16 Vt[64 * PSTR];
  const int tid = threadIdx.x;
  const int w = tid >> 6, l = tid & 63;
  const int lg = l >> 4, lc = l & 15;
  const int qt = blockIdx.x & 7;
  const int bh = blockIdx.x >> 3;
  const int h = bh % 12;
  const int b = bh / 12;
  const int q0 = qt * 64;
  const u16* qp = q + (size_t)bh * 512 * 64;
  const u16* kp = k + (size_t)bh * 512 * 64;
  const u16* vp = v + (size_t)bh * 512 * 64;

  // stage V transposed: Vt[d][key]
  for (int it = 0; it < 32; ++it) {
    int idx4 = (it * 256 + tid) * 4;
    int kk = idx4 >> 6, d0 = idx4 & 63;
    uint2 val = *reinterpret_cast<const uint2*>(vp + idx4);
    Vt[(d0 + 0) * PSTR + kk] = (u16)(val.x & 0xffffu);
    Vt[(d0 + 1) * PSTR + kk] = (u16)(val.x >> 16);
    Vt[(d0 + 2) * PSTR + kk] = (u16)(val.y & 0xffffu);
    Vt[(d0 + 3) * PSTR + kk] = (u16)(val.y >> 16);
  }

  // Phase A: S = Q K^T (+bias), full-row softmax in registers
  bf16x8 aq[2];
#pragma unroll
  for (int kk = 0; kk < 2; ++kk)
    aq[kk] = *reinterpret_cast<const bf16x8*>(qp + (q0 + w * 16 + lc) * 64 + kk * 32 + lg * 8);

  f32x4 s[32] = {};
#pragma unroll
  for (int kt = 0; kt < 32; ++kt) {
    bf16x8 b0 = *reinterpret_cast<const bf16x8*>(kp + (kt * 16 + lc) * 64 + lg * 8);
    bf16x8 b1 = *reinterpret_cast<const bf16x8*>(kp + (kt * 16 + lc) * 64 + 32 + lg * 8);
    s[kt] = __builtin_amdgcn_mfma_f32_16x16x32_bf16(aq[0], b0, s[kt], 0, 0, 0);
    s[kt] = __builtin_amdgcn_mfma_f32_16x16x32_bf16(aq[1], b1, s[kt], 0, 0, 0);
  }

  const float* bp = eb + (size_t)h * 512 * 512 + (size_t)(q0 + w * 16 + lg * 4) * 512 + lc;
#pragma unroll
  for (int kt = 0; kt < 32; ++kt)
#pragma unroll
    for (int r = 0; r < 4; ++r)
      s[kt][r] += bp[r * 512 + kt * 16];

  float mrow[4], inv[4];
#pragma unroll
  for (int r = 0; r < 4; ++r) {
    float m = s[0][r];
#pragma unroll
    for (int kt = 1; kt < 32; ++kt) m = fmaxf(m, s[kt][r]);
    m = fmaxf(m, __shfl_xor(m, 1));
    m = fmaxf(m, __shfl_xor(m, 2));
    m = fmaxf(m, __shfl_xor(m, 4));
    m = fmaxf(m, __shfl_xor(m, 8));
    mrow[r] = m;
  }
#pragma unroll
  for (int r = 0; r < 4; ++r) {
    float sum = 0.f;
#pragma unroll
    for (int kt = 0; kt < 32; ++kt) {
      float pv = __expf(s[kt][r] - mrow[r]);
      s[kt][r] = pv;
      sum += pv;
    }
    sum += __shfl_xor(sum, 1);
    sum += __shfl_xor(sum, 2);
    sum += __shfl_xor(sum, 4);
    sum += __shfl_xor(sum, 8);
    inv[r] = 1.0f / sum;
  }
#pragma unroll
  for (int kt = 0; kt < 32; ++kt)
#pragma unroll
    for (int r = 0; r < 4; ++r)
      P[(w * 16 + lg * 4 + r) * PSTR + kt * 16 + lc] = f2bf(s[kt][r] * inv[r]);

  __syncthreads();

  // Phase B: O = P @ V
  f32x4 oa[4] = {};
#pragma unroll
  for (int ks = 0; ks < 16; ++ks) {
    bf16x8 pa = *reinterpret_cast<const bf16x8*>(&P[(w * 16 + lc) * PSTR + ks * 32 + lg * 8]);
#pragma unroll
    for (int ni = 0; ni < 4; ++ni) {
      bf16x8 bv = *reinterpret_cast<const bf16x8*>(&Vt[(ni * 16 + lc) * PSTR + ks * 32 + lg * 8]);
      oa[ni] = __builtin_amdgcn_mfma_f32_16x16x32_bf16(pa, bv, oa[ni], 0, 0, 0);
    }
  }

  u16* op = o + ((size_t)(b * 512 + q0)) * 768 + h * 64;
#pragma unroll
  for (int ni = 0; ni < 4; ++ni)
#pragma unroll
    for (int r = 0; r < 4; ++r)
      op[(size_t)(w * 16 + lg * 4 + r) * 768 + ni * 16 + lc] = f2bf(oa[ni][r]);
}

// ---------- launch ----------
extern "C" void kernel_launch(void* const* d_in, const int* in_sizes, int n_in,
                              void* d_out, int out_size, void* d_ws, size_t ws_size,
                              hipStream_t stream) {
  const float* x     = (const float*)d_in[0];
  const float* ebias = (const float*)d_in[1];
  const float* ln1g  = (const float*)d_in[2];
  const float* ln1b  = (const float*)d_in[3];
  const float* qkvw  = (const float*)d_in[4];
  const float* qkvb  = (const float*)d_in[5];
  const float* projw = (const float*)d_in[6];
  const float* projb = (const float*)d_in[7];
  const float* ln2g  = (const float*)d_in[8];
  const float* ln2b  = (const float*)d_in[9];
  const float* fc1w  = (const float*)d_in[10];
  const float* fc1b  = (const float*)d_in[11];
  const float* fc2w  = (const float*)d_in[12];
  const float* fc2b  = (const float*)d_in[13];
  float* out = (float*)d_out;

  char* p = (char*)d_ws;
  const size_t ACT = (size_t)16384 * 768 * 2;  // 25165824 B
  u16* xnb = (u16*)(p);                        // xn, later attn_out
  u16* qb  = (u16*)(p + ACT);
  u16* kb  = (u16*)(p + 2 * ACT);              // k, later ln2 output
  u16* vb  = (u16*)(p + 3 * ACT);
  u16* ffb = (u16*)(p + 4 * ACT);              // 100663296 B
  float* x2 = (float*)(p + 4 * ACT + (size_t)16384 * 3072 * 2);
  char* wz = p + 4 * ACT + (size_t)16384 * 3072 * 2 + (size_t)16384 * 768 * 4;
  u16* wq  = (u16*)wz;
  u16* wp  = wq + (size_t)2304 * 768;
  u16* wf1 = wp + (size_t)768 * 768;
  u16* wf2 = wf1 + (size_t)3072 * 768;

  cvt_bf16<<<1728, 256, 0, stream>>>(qkvw, wq, 442368);
  cvt_bf16<<<576, 256, 0, stream>>>(projw, wp, 147456);
  cvt_bf16<<<2304, 256, 0, stream>>>(fc1w, wf1, 589824);
  cvt_bf16<<<2304, 256, 0, stream>>>(fc2w, wf2, 589824);

  ln_bf16<<<16384, 256, 0, stream>>>(x, ln1g, ln1b, xnb);

  gemm_bt<EPI_QKV><<<dim3(128, 18), 256, 0, stream>>>(
      xnb, wq, qkvb, nullptr, nullptr, nullptr, qb, kb, vb, 16384, 2304, 768);

  attn_fwd<<<3072, 256, 0, stream>>>(qb, kb, vb, ebias, xnb);

  gemm_bt<EPI_PROJ><<<dim3(128, 6), 256, 0, stream>>>(
      xnb, wp, projb, x, x2, nullptr, nullptr, nullptr, nullptr, 16384, 768, 768);

  ln_bf16<<<16384, 256, 0, stream>>>(x2, ln2g, ln2b, kb);

  gemm_bt<EPI_GELU><<<dim3(128, 24), 256, 0, stream>>>(
      kb, wf1, fc1b, nullptr, nullptr, ffb, nullptr, nullptr, nullptr, 16384, 3072, 768);

  gemm_bt<EPI_OUT><<<dim3(128, 6), 256, 0, stream>>>(
      ffb, wf2, fc2b, x2, out, nullptr, nullptr, nullptr, nullptr, 16384, 768, 3072);
}